// Round 1
// baseline (138.949 us; speedup 1.0000x reference)
//
#include <hip/hip_runtime.h>
#include <hip/hip_bf16.h>
#include <math.h>

#define NN 55
#define KK 8192
#define OO 8192

using bf16x8 = __attribute__((ext_vector_type(8))) __bf16;
using f32x4  = __attribute__((ext_vector_type(4))) float;

__device__ inline bf16x8 cvt8(f32x4 lo, f32x4 hi) {
    bf16x8 v;
    v[0] = (__bf16)lo[0]; v[1] = (__bf16)lo[1];
    v[2] = (__bf16)lo[2]; v[3] = (__bf16)lo[3];
    v[4] = (__bf16)hi[0]; v[5] = (__bf16)hi[1];
    v[6] = (__bf16)hi[2]; v[7] = (__bf16)hi[3];
    return v;
}

// out = elu(x @ W1^T + b1)
// grid = 512 blocks (one 16-col o-tile each), block = 512 threads (8 waves).
// Wave w handles K range [w*1024, (w+1)*1024) for all 4 m-tiles (rows 0..63,
// 55..63 zero-padded). Partial accs reduced across waves via LDS, then
// bias + ELU + store.
__global__ __launch_bounds__(512, 4)
void gat_gemm_elu(const float* __restrict__ xg,
                  const float* __restrict__ wg,
                  const float* __restrict__ bg,
                  float* __restrict__ outg) {
    __shared__ float lds[8 * 1024];

    const int tid  = threadIdx.x;
    const int lane = tid & 63;
    const int w    = tid >> 6;      // wave id 0..7
    const int r    = lane & 15;     // row/col within fragment
    const int q    = lane >> 4;     // 0..3 -> k-subgroup

    const int obase = blockIdx.x * 16;
    const int o     = obase + r;

    // this wave's starting k (includes the per-lane q*8 fragment offset)
    const int kb0 = w * 1024 + q * 8;

    const float* bptr = wg + (size_t)o * KK + kb0;

    // A (x) base pointers per m-tile; rows >= 55 masked to zero fragments
    const float* aptr[4];
    bool amask[4];
#pragma unroll
    for (int mt = 0; mt < 4; ++mt) {
        const int arow = mt * 16 + r;
        amask[mt] = (arow < NN);
        aptr[mt]  = xg + (size_t)(amask[mt] ? arow : 0) * KK + kb0;
    }

    f32x4 acc[4] = {};

#pragma unroll 4
    for (int s = 0; s < 32; ++s) {
        const float* bp = bptr + s * 32;
        const f32x4 b0 = *(const f32x4*)(bp);
        const f32x4 b1 = *(const f32x4*)(bp + 4);
        const bf16x8 bf = cvt8(b0, b1);

#pragma unroll
        for (int mt = 0; mt < 4; ++mt) {
            bf16x8 af = {};
            if (amask[mt]) {
                const float* ap = aptr[mt] + s * 32;
                const f32x4 a0 = *(const f32x4*)(ap);
                const f32x4 a1 = *(const f32x4*)(ap + 4);
                af = cvt8(a0, a1);
            }
            acc[mt] = __builtin_amdgcn_mfma_f32_16x16x32_bf16(af, bf, acc[mt], 0, 0, 0);
        }
    }

    // stash this wave's 64x16 partial tile: C row = mt*16 + q*4 + e, col = r
#pragma unroll
    for (int mt = 0; mt < 4; ++mt) {
#pragma unroll
        for (int e = 0; e < 4; ++e) {
            lds[w * 1024 + (mt * 16 + q * 4 + e) * 16 + r] = acc[mt][e];
        }
    }
    __syncthreads();

    // reduce across 8 waves, add bias, ELU, store rows < 55
#pragma unroll
    for (int i = tid; i < 1024; i += 512) {
        float s = 0.f;
#pragma unroll
        for (int ww = 0; ww < 8; ++ww) s += lds[ww * 1024 + i];
        const int row = i >> 4;
        const int col = i & 15;
        const float v = s + bg[obase + col];
        const float res = (v > 0.f) ? v : expm1f(v);
        if (row < NN) outg[(size_t)row * OO + obase + col] = res;
    }
}

extern "C" void kernel_launch(void* const* d_in, const int* in_sizes, int n_in,
                              void* d_out, int out_size, void* d_ws, size_t ws_size,
                              hipStream_t stream) {
    const float* x  = (const float*)d_in[0];
    const float* W1 = (const float*)d_in[3];
    const float* b1 = (const float*)d_in[4];
    float* out = (float*)d_out;

    gat_gemm_elu<<<dim3(OO / 16), dim3(512), 0, stream>>>(x, W1, b1, out);
}

// Round 2
// 77.646 us; speedup vs baseline: 1.7895x; 1.7895x over previous
//
#include <hip/hip_runtime.h>
#include <hip/hip_bf16.h>
#include <math.h>

#define NN 55
#define KK 8192
#define OO 8192

using bf16x8 = __attribute__((ext_vector_type(8))) __bf16;
using f32x4  = __attribute__((ext_vector_type(4))) float;

__device__ inline bf16x8 cvt8(f32x4 lo, f32x4 hi) {
    bf16x8 v;
    v[0] = (__bf16)lo[0]; v[1] = (__bf16)lo[1];
    v[2] = (__bf16)lo[2]; v[3] = (__bf16)lo[3];
    v[4] = (__bf16)hi[0]; v[5] = (__bf16)hi[1];
    v[6] = (__bf16)hi[2]; v[7] = (__bf16)hi[3];
    return v;
}

// Kernel 1: x [55,8192] f32 -> xb [64,8192] bf16, rows 55..63 zeroed.
__global__ __launch_bounds__(256)
void cvt_x(const float* __restrict__ xg, __bf16* __restrict__ xb) {
    const int idx = blockIdx.x * 256 + threadIdx.x;   // 0..65535, one per 8 elems
    const int row = idx >> 10;
    const int c8  = (idx & 1023) * 8;
    bf16x8 v = {};
    if (row < NN) {
        const float* p = xg + (size_t)row * KK + c8;
        v = cvt8(*(const f32x4*)p, *(const f32x4*)(p + 4));
    }
    *(bf16x8*)(xb + (size_t)row * KK + c8) = v;
}

// Kernel 2: out = elu(x @ W^T + b).
// 256 blocks x 512 threads. Block owns 32 output cols (2 o-subtiles of 16).
// Wave w (0..7) owns K range [w*1024, (w+1)*1024), 32 k-steps of 32.
// Explicit depth-1 prefetch: next iter's 8 loads issued before current cvt+MFMA.
// Cross-wave f32 reduce in 64KB LDS, then bias + ELU + store.
__global__ __launch_bounds__(512, 4)
void gat_gemm_elu2(const __bf16* __restrict__ xb,
                   const float* __restrict__ wg,
                   const float* __restrict__ bg,
                   float* __restrict__ outg) {
    __shared__ float lds[8 * 2048];

    const int tid  = threadIdx.x;
    const int lane = tid & 63;
    const int w    = tid >> 6;     // wave 0..7
    const int r    = lane & 15;
    const int q    = lane >> 4;

    const int obase = blockIdx.x * 32;
    const int kb0   = w * 1024 + q * 8;

    const float* wp0 = wg + (size_t)(obase + r) * KK + kb0;        // o-subtile 0
    const float* wp1 = wp0 + (size_t)16 * KK;                      // o-subtile 1
    const __bf16* ap = xb + (size_t)r * KK + kb0;                  // m-tile stride 16*KK

    f32x4 acc0[4] = {};
    f32x4 acc1[4] = {};

    // prologue: load k-step 0
    f32x4 cw0 = *(const f32x4*)(wp0);
    f32x4 cw1 = *(const f32x4*)(wp0 + 4);
    f32x4 cw2 = *(const f32x4*)(wp1);
    f32x4 cw3 = *(const f32x4*)(wp1 + 4);
    bf16x8 ca0 = *(const bf16x8*)(ap);
    bf16x8 ca1 = *(const bf16x8*)(ap + (size_t)16 * KK);
    bf16x8 ca2 = *(const bf16x8*)(ap + (size_t)32 * KK);
    bf16x8 ca3 = *(const bf16x8*)(ap + (size_t)48 * KK);

    for (int s = 0; s < 32; ++s) {
        const int sn = (s + 1) & 31;   // last iter wraps to 0: harmless in-bounds reload
        // issue next-iter loads first (8 independent 16B loads in flight)
        const f32x4 nw0 = *(const f32x4*)(wp0 + sn * 32);
        const f32x4 nw1 = *(const f32x4*)(wp0 + sn * 32 + 4);
        const f32x4 nw2 = *(const f32x4*)(wp1 + sn * 32);
        const f32x4 nw3 = *(const f32x4*)(wp1 + sn * 32 + 4);
        const bf16x8 na0 = *(const bf16x8*)(ap + sn * 32);
        const bf16x8 na1 = *(const bf16x8*)(ap + (size_t)16 * KK + sn * 32);
        const bf16x8 na2 = *(const bf16x8*)(ap + (size_t)32 * KK + sn * 32);
        const bf16x8 na3 = *(const bf16x8*)(ap + (size_t)48 * KK + sn * 32);

        // consume current (loaded last iter; compiler waits with counted vmcnt)
        const bf16x8 b0 = cvt8(cw0, cw1);
        const bf16x8 b1 = cvt8(cw2, cw3);
        acc0[0] = __builtin_amdgcn_mfma_f32_16x16x32_bf16(ca0, b0, acc0[0], 0, 0, 0);
        acc1[0] = __builtin_amdgcn_mfma_f32_16x16x32_bf16(ca0, b1, acc1[0], 0, 0, 0);
        acc0[1] = __builtin_amdgcn_mfma_f32_16x16x32_bf16(ca1, b0, acc0[1], 0, 0, 0);
        acc1[1] = __builtin_amdgcn_mfma_f32_16x16x32_bf16(ca1, b1, acc1[1], 0, 0, 0);
        acc0[2] = __builtin_amdgcn_mfma_f32_16x16x32_bf16(ca2, b0, acc0[2], 0, 0, 0);
        acc1[2] = __builtin_amdgcn_mfma_f32_16x16x32_bf16(ca2, b1, acc1[2], 0, 0, 0);
        acc0[3] = __builtin_amdgcn_mfma_f32_16x16x32_bf16(ca3, b0, acc0[3], 0, 0, 0);
        acc1[3] = __builtin_amdgcn_mfma_f32_16x16x32_bf16(ca3, b1, acc1[3], 0, 0, 0);

        cw0 = nw0; cw1 = nw1; cw2 = nw2; cw3 = nw3;
        ca0 = na0; ca1 = na1; ca2 = na2; ca3 = na3;
    }

    // stash partials: wave w's 64x32 tile. C row = mt*16 + q*4 + e, col = r (+16 for ot1)
#pragma unroll
    for (int mt = 0; mt < 4; ++mt) {
#pragma unroll
        for (int e = 0; e < 4; ++e) {
            const int row = mt * 16 + q * 4 + e;
            lds[w * 2048 + row * 32 + r]      = acc0[mt][e];
            lds[w * 2048 + row * 32 + 16 + r] = acc1[mt][e];
        }
    }
    __syncthreads();

    // reduce 8 waves, bias, ELU, store rows < 55
    for (int i = tid; i < 2048; i += 512) {
        float s = 0.f;
#pragma unroll
        for (int ww = 0; ww < 8; ++ww) s += lds[ww * 2048 + i];
        const int row = i >> 5;
        const int col = i & 31;
        const float v = s + bg[obase + col];
        const float res = (v > 0.f) ? v : expm1f(v);
        if (row < NN) outg[(size_t)row * OO + obase + col] = res;
    }
}

extern "C" void kernel_launch(void* const* d_in, const int* in_sizes, int n_in,
                              void* d_out, int out_size, void* d_ws, size_t ws_size,
                              hipStream_t stream) {
    const float* x  = (const float*)d_in[0];
    const float* W1 = (const float*)d_in[3];
    const float* b1 = (const float*)d_in[4];
    float* out = (float*)d_out;
    __bf16* xb = (__bf16*)d_ws;   // 64*8192*2 = 1 MB

    cvt_x<<<dim3(256), dim3(256), 0, stream>>>(x, xb);
    gat_gemm_elu2<<<dim3(OO / 32), dim3(512), 0, stream>>>(xb, W1, b1, out);
}

// Round 3
// 62.636 us; speedup vs baseline: 2.2183x; 1.2396x over previous
//
#include <hip/hip_runtime.h>
#include <hip/hip_bf16.h>
#include <math.h>

#define NN 55
#define KK 8192
#define OO 8192

using bf16x8 = __attribute__((ext_vector_type(8))) __bf16;
using f32x4  = __attribute__((ext_vector_type(4))) float;

__device__ inline bf16x8 cvt8(f32x4 lo, f32x4 hi) {
    bf16x8 v;
    v[0] = (__bf16)lo[0]; v[1] = (__bf16)lo[1];
    v[2] = (__bf16)lo[2]; v[3] = (__bf16)lo[3];
    v[4] = (__bf16)hi[0]; v[5] = (__bf16)hi[1];
    v[6] = (__bf16)hi[2]; v[7] = (__bf16)hi[3];
    return v;
}

// Kernel 1: x [55,8192] f32 -> xb [64,8192] bf16, rows 55..63 zeroed.
__global__ __launch_bounds__(256)
void cvt_x(const float* __restrict__ xg, __bf16* __restrict__ xb) {
    const int idx = blockIdx.x * 256 + threadIdx.x;
    const int row = idx >> 10;
    const int c8  = (idx & 1023) * 8;
    bf16x8 v = {};
    if (row < NN) {
        const float* p = xg + (size_t)row * KK + c8;
        v = cvt8(*(const f32x4*)p, *(const f32x4*)(p + 4));
    }
    *(bf16x8*)(xb + (size_t)row * KK + c8) = v;
}

__device__ inline void gll16(const float* src, float* dstLds) {
    __builtin_amdgcn_global_load_lds(
        (const __attribute__((address_space(1))) void*)src,
        (__attribute__((address_space(3))) void*)dstLds, 16, 0, 0);
}

#define WAITVM(N) asm volatile("s_waitcnt vmcnt(" #N ")" ::: "memory")
#define BAR() __builtin_amdgcn_s_barrier()

// Kernel 2: out = elu(x @ W^T + b).
// 256 blocks x 512 threads (8 waves), o-tile 32 W-rows per block.
// K in 32 stages of 256. W staged to LDS via global_load_lds (contiguous 1KB
// row-chunks, pre-swizzled global source; XOR-swizzled ds_read). 4-deep
// multi-buffer, counted vmcnt(16), raw barriers (1 per stage). Wave w
// computes k-slice [w*32, w*32+32) of each stage; A-frags register-prefetched
// depth-3 from L2-resident xb. Cross-wave f32 reduce in LDS at the end.
__global__ __launch_bounds__(512, 2)
void gat_gemm_elu3(const __bf16* __restrict__ xb,
                   const float* __restrict__ wg,
                   const float* __restrict__ bg,
                   float* __restrict__ outg) {
    __shared__ float Wbuf[4 * 8192];   // 128 KiB: 4 bufs x (32 rows x 256 f32)

    const int tid  = threadIdx.x;
    const int lane = tid & 63;
    const int w    = tid >> 6;
    const int r    = lane & 15;
    const int q    = lane >> 4;
    const int w4   = w * 4;
    const int obase = blockIdx.x * 32;

    // Per-lane pre-swizzled W source bases: stage row lr = w4+j holds, at LDS
    // chunk c, the global chunk c ^ (lr&7)  (16B chunks within the 1KB row).
    const float* wsrc[4];
#pragma unroll
    for (int j = 0; j < 4; ++j) {
        const int lr = w4 + j;
        wsrc[j] = wg + (size_t)(obase + lr) * KK + ((lane ^ (lr & 7)) << 2);
    }
    const __bf16* abase = xb + (size_t)r * KK + w * 32 + q * 8;

    const int sw  = (r & 7) << 4;
    const int kx0 = (w * 128 + q * 32) ^ sw;
    const int kx1 = (w * 128 + q * 32 + 16) ^ sw;

    f32x4 acc0[4] = {};
    f32x4 acc1[4] = {};
    bf16x8 A0[4], A1[4], A2[4], A3[4];

#define STAGE_W(BUF, STG) do {                                              \
    const int kb_ = (STG) * 256;                                            \
    _Pragma("unroll")                                                       \
    for (int j = 0; j < 4; ++j) {                                           \
        gll16(wsrc[j] + kb_, &Wbuf[(BUF) * 8192 + (w4 + j) * 256]);         \
    } } while (0)

#define LOAD_A(SLOT, STG) do {                                              \
    const __bf16* a_ = abase + (size_t)(STG) * 256;                         \
    SLOT[0] = *(const bf16x8*)(a_);                                         \
    SLOT[1] = *(const bf16x8*)(a_ + (size_t)16 * KK);                       \
    SLOT[2] = *(const bf16x8*)(a_ + (size_t)32 * KK);                       \
    SLOT[3] = *(const bf16x8*)(a_ + (size_t)48 * KK); } while (0)

#define COMPUTE(BUF, AS) do {                                               \
    const char* wb_ = (const char*)&Wbuf[(BUF) * 8192];                     \
    const f32x4 lo0 = *(const f32x4*)(wb_ + r * 1024 + kx0);                \
    const f32x4 hi0 = *(const f32x4*)(wb_ + r * 1024 + kx1);                \
    const f32x4 lo1 = *(const f32x4*)(wb_ + (16 + r) * 1024 + kx0);         \
    const f32x4 hi1 = *(const f32x4*)(wb_ + (16 + r) * 1024 + kx1);         \
    const bf16x8 b0 = cvt8(lo0, hi0);                                       \
    const bf16x8 b1 = cvt8(lo1, hi1);                                       \
    acc0[0] = __builtin_amdgcn_mfma_f32_16x16x32_bf16(AS[0], b0, acc0[0], 0, 0, 0); \
    acc1[0] = __builtin_amdgcn_mfma_f32_16x16x32_bf16(AS[0], b1, acc1[0], 0, 0, 0); \
    acc0[1] = __builtin_amdgcn_mfma_f32_16x16x32_bf16(AS[1], b0, acc0[1], 0, 0, 0); \
    acc1[1] = __builtin_amdgcn_mfma_f32_16x16x32_bf16(AS[1], b1, acc1[1], 0, 0, 0); \
    acc0[2] = __builtin_amdgcn_mfma_f32_16x16x32_bf16(AS[2], b0, acc0[2], 0, 0, 0); \
    acc1[2] = __builtin_amdgcn_mfma_f32_16x16x32_bf16(AS[2], b1, acc1[2], 0, 0, 0); \
    acc0[3] = __builtin_amdgcn_mfma_f32_16x16x32_bf16(AS[3], b0, acc0[3], 0, 0, 0); \
    acc1[3] = __builtin_amdgcn_mfma_f32_16x16x32_bf16(AS[3], b1, acc1[3], 0, 0, 0); \
    } while (0)

    // prologue: stages 0,1,2 in flight (8 VMEM per stage-window)
    STAGE_W(0, 0); LOAD_A(A0, 0);
    STAGE_W(1, 1); LOAD_A(A1, 1);
    STAGE_W(2, 2); LOAD_A(A2, 2);

    int s = 0;
#pragma unroll 1
    for (int su = 0; su < 7; ++su) {
        WAITVM(16); BAR(); STAGE_W(3, s + 3); LOAD_A(A3, s + 3); COMPUTE(0, A0);
        WAITVM(16); BAR(); STAGE_W(0, s + 4); LOAD_A(A0, s + 4); COMPUTE(1, A1);
        WAITVM(16); BAR(); STAGE_W(1, s + 5); LOAD_A(A1, s + 5); COMPUTE(2, A2);
        WAITVM(16); BAR(); STAGE_W(2, s + 6); LOAD_A(A2, s + 6); COMPUTE(3, A3);
        s += 4;
    }
    // tail: s = 28..31
    WAITVM(16); BAR(); STAGE_W(3, 31); LOAD_A(A3, 31); COMPUTE(0, A0);
    WAITVM(16); BAR(); COMPUTE(1, A1);
    WAITVM(8);  BAR(); COMPUTE(2, A2);
    WAITVM(0);  BAR(); COMPUTE(3, A3);

    // cross-wave reduce: alias first 64KB of Wbuf (bufs 0,1; disjoint from buf3)
    float* red = Wbuf;
#pragma unroll
    for (int mt = 0; mt < 4; ++mt) {
#pragma unroll
        for (int e = 0; e < 4; ++e) {
            const int row = mt * 16 + q * 4 + e;
            red[w * 2048 + row * 32 + r]      = acc0[mt][e];
            red[w * 2048 + row * 32 + 16 + r] = acc1[mt][e];
        }
    }
    __syncthreads();

    for (int i = tid; i < 2048; i += 512) {
        float ssum = 0.f;
#pragma unroll
        for (int ww = 0; ww < 8; ++ww) ssum += red[ww * 2048 + i];
        const int row = i >> 5;
        const int col = i & 31;
        const float v = ssum + bg[obase + col];
        const float res = (v > 0.f) ? v : expm1f(v);
        if (row < NN) outg[(size_t)row * OO + obase + col] = res;
    }
#undef STAGE_W
#undef LOAD_A
#undef COMPUTE
}

extern "C" void kernel_launch(void* const* d_in, const int* in_sizes, int n_in,
                              void* d_out, int out_size, void* d_ws, size_t ws_size,
                              hipStream_t stream) {
    const float* x  = (const float*)d_in[0];
    const float* W1 = (const float*)d_in[3];
    const float* b1 = (const float*)d_in[4];
    float* out = (float*)d_out;
    __bf16* xb = (__bf16*)d_ws;   // 64*8192*2 = 1 MB

    cvt_x<<<dim3(256), dim3(256), 0, stream>>>(x, xb);
    gat_gemm_elu3<<<dim3(OO / 32), dim3(512), 0, stream>>>(xb, W1, b1, out);
}